// Round 1
// baseline (644.173 us; speedup 1.0000x reference)
//
#include <hip/hip_runtime.h>
#include <cstddef>

#define B_ 64
#define H_ 1024
#define L_ 400
#define V_ 50000
#define VP_ 50500   // V + OOV_PAD
#define NBV_ 782    // vocab gemm blocks: 782*64 = 50048 >= 50000
#define BMXW_ 800   // padded row width of BMX

typedef short short8 __attribute__((ext_vector_type(8)));
typedef float f32x4 __attribute__((ext_vector_type(4)));

static __device__ __forceinline__ short f2bf(float f) {
  unsigned u = __float_as_uint(f);
  u += 0x7fffu + ((u >> 16) & 1u);   // round-to-nearest-even
  return (short)(u >> 16);
}

static __device__ __forceinline__ short8 pack8(float4 a, float4 b) {
  short8 r;
  r[0] = f2bf(a.x); r[1] = f2bf(a.y); r[2] = f2bf(a.z); r[3] = f2bf(a.w);
  r[4] = f2bf(b.x); r[5] = f2bf(b.y); r[6] = f2bf(b.z); r[7] = f2bf(b.w);
  return r;
}

// Job descriptor for the small-GEMM kernel.
// X (the 64-row activation) is concat(Xa, Xb) along K: k<1024 -> Xa, k>=1024 -> Xb.
// gather!=0: Xa rows come from emb[ids[m]] instead of Xa + m*H.
struct Job {
  const float* W; const float* bias; const float* Xa; const float* Xb;
  float* out; int N; int K; int ldo; int gather;
};

// ---------------- small GEMM: out[m=0..63][n] = sum_k X[m][k]*W[n][k] + bias[n]
// Block = 16 n-cols, 4 waves K-split 4-way, LDS cross-wave reduce.
// Two jobs per launch (block ranges [0,c0) and [c0,c0+c1)); blocks >= c0+c1
// compute p_gen (one batch row each).
__global__ __launch_bounds__(256) void k_gemm2(
    Job j0, int c0, Job j1, int c1,
    const int* __restrict__ ids, const float* __restrict__ emb,
    const float* __restrict__ pg_C, const float* __restrict__ pg_hid,
    const float* __restrict__ gW, const float* __restrict__ gb,
    float* __restrict__ PG) {
  __shared__ float red[4][64][16];   // 16 KB
  __shared__ int sid[64];
  __shared__ float redp[256];
  int bid = blockIdx.x, tid = threadIdx.x;

  if (bid >= c0 + c1) {              // ---- p_gen block: sigmoid(gen_W . [C, h0])
    int b = bid - c0 - c1;
    float acc = 0.f;
    for (int k = tid; k < 2 * H_; k += 256) {
      float x = (k < H_) ? pg_C[b * H_ + k] : pg_hid[b * H_ + k - H_];
      acc += x * gW[k];
    }
    redp[tid] = acc; __syncthreads();
    for (int s = 128; s > 0; s >>= 1) { if (tid < s) redp[tid] += redp[tid + s]; __syncthreads(); }
    if (tid == 0) PG[b] = 1.f / (1.f + __expf(-(redp[0] + gb[0])));
    return;
  }

  Job J = (bid < c0) ? j0 : j1;
  int bx = (bid < c0) ? bid : bid - c0;
  if (tid < 64) sid[tid] = ids[tid];
  __syncthreads();

  int wave = tid >> 6, lane = tid & 63;
  int q = lane >> 4, nl = lane & 15;
  int n = bx * 16 + nl;
  int nld = n < J.N ? n : (J.N - 1);
  int kpw = J.K >> 2;
  int kbeg = wave * kpw;
  const float* wr = J.W + (size_t)nld * J.K;

  f32x4 acc[4];
  #pragma unroll
  for (int i = 0; i < 4; ++i) acc[i] = (f32x4){0.f, 0.f, 0.f, 0.f};

  for (int k0 = kbeg; k0 < kbeg + kpw; k0 += 32) {
    int kk = k0 + q * 8;                     // halves never straddle (32 | 1024)
    float4 w0 = *(const float4*)(wr + kk);
    float4 w1 = *(const float4*)(wr + kk + 4);
    short8 bf = pack8(w0, w1);
    #pragma unroll
    for (int mt = 0; mt < 4; ++mt) {
      int m = mt * 16 + nl;
      const float* xp;
      if (kk < H_) xp = (J.gather ? emb + (size_t)sid[m] * H_
                                  : J.Xa + (size_t)m * H_) + kk;
      else         xp = J.Xb + (size_t)m * H_ + (kk - H_);
      float4 x0 = *(const float4*)xp;
      float4 x1 = *(const float4*)(xp + 4);
      short8 af = pack8(x0, x1);
      acc[mt] = __builtin_amdgcn_mfma_f32_16x16x32_bf16(af, bf, acc[mt], 0, 0, 0);
    }
  }

  #pragma unroll
  for (int mt = 0; mt < 4; ++mt)
    #pragma unroll
    for (int r = 0; r < 4; ++r)
      red[wave][mt * 16 + q * 4 + r][nl] = acc[mt][r];
  __syncthreads();
  for (int i = tid; i < 1024; i += 256) {
    int m = i >> 4, c2 = i & 15;
    int nn = bx * 16 + c2;
    if (nn < J.N) {
      float s = red[0][m][c2] + red[1][m][c2] + red[2][m][c2] + red[3][m][c2] + J.bias[nn];
      J.out[(size_t)m * J.ldo + nn] = s;
    }
  }
}

// ---------------- attention softmax + apply, atomic-free.
// grid (9, 64): hc<8 own a 128-col h-slice of A over all 400 L positions;
// hc==8 writes aw_out, copies hidden->output, zeroes SE64 accumulator.
__global__ __launch_bounds__(256) void k_attnsm2(
    const float* __restrict__ S, const float* __restrict__ enc,
    float* __restrict__ aw_out, float* __restrict__ A,
    const float* __restrict__ hid, float* __restrict__ hid_out,
    float* __restrict__ SE64) {
  __shared__ float w[L_];
  __shared__ float red[256];
  __shared__ float4 rv[256];
  int hc = blockIdx.x, b = blockIdx.y, t = threadIdx.x;

  float a0 = S[b * L_ + t];                          // t < 256 < 400
  float a1 = (t < L_ - 256) ? S[b * L_ + 256 + t] : -1e30f;
  float m = fmaxf(a0, a1);
  red[t] = m; __syncthreads();
  for (int s = 128; s > 0; s >>= 1) { if (t < s) red[t] = fmaxf(red[t], red[t + s]); __syncthreads(); }
  m = red[0]; __syncthreads();
  float e0 = __expf(a0 - m);
  float e1 = (t < L_ - 256) ? __expf(a1 - m) : 0.f;
  red[t] = e0 + e1; __syncthreads();
  for (int s = 128; s > 0; s >>= 1) { if (t < s) red[t] += red[t + s]; __syncthreads(); }
  float z = red[0];
  w[t] = e0 / z;
  if (t < L_ - 256) w[256 + t] = e1 / z;
  __syncthreads();

  if (hc == 8) {
    aw_out[b * L_ + t] = w[t];
    if (t < L_ - 256) aw_out[b * L_ + 256 + t] = w[256 + t];
    ((float4*)(hid_out + (size_t)b * H_))[t] = ((const float4*)(hid + (size_t)b * H_))[t];
    if (b == 0 && t < 64) SE64[t] = 0.f;
    return;
  }

  int cq = t & 31, lg = t >> 5;                      // 32 col-quads x 8 l-groups
  float4 acc = make_float4(0.f, 0.f, 0.f, 0.f);
  const float* base = enc + (size_t)b * H_ + hc * 128 + cq * 4;
  #pragma unroll 5
  for (int l = lg; l < L_; l += 8) {
    float wg = w[l];
    float4 e = *(const float4*)(base + (size_t)l * B_ * H_);
    acc.x += wg * e.x; acc.y += wg * e.y; acc.z += wg * e.z; acc.w += wg * e.w;
  }
  rv[t] = acc; __syncthreads();
  if (t < 32) {
    float4 s = rv[t];
    #pragma unroll
    for (int g = 1; g < 8; ++g) {
      float4 o = rv[g * 32 + t];
      s.x += o.x; s.y += o.y; s.z += o.z; s.w += o.w;
    }
    *(float4*)(A + (size_t)b * H_ + hc * 128 + t * 4) = s;
  }
}

// ---------------- GRU elementwise: h_new -> bf16
__global__ __launch_bounds__(256) void k_gru(
    const float* __restrict__ gi, const float* __restrict__ gh,
    const float* __restrict__ hid, short* __restrict__ HNb) {
  int idx = blockIdx.x * 256 + threadIdx.x;          // 65536
  int b = idx >> 10, h = idx & 1023;
  float ir = gi[b * 3072 + h], iz = gi[b * 3072 + 1024 + h], inn = gi[b * 3072 + 2048 + h];
  float hr = gh[b * 3072 + h], hz = gh[b * 3072 + 1024 + h], hn = gh[b * 3072 + 2048 + h];
  float r = 1.f / (1.f + __expf(-(ir + hr)));
  float z = 1.f / (1.f + __expf(-(iz + hz)));
  float n = tanhf(inn + r * hn);
  HNb[idx] = f2bf((1.f - z) * n + z * hid[idx]);
}

// ---------------- vocab GEMM + fused per-block row-max -> BMX[64][800]
__global__ __launch_bounds__(256) void k_gemm_vocab(
    const short* __restrict__ Xb, const float* __restrict__ W,
    const float* __restrict__ bias, float* __restrict__ P,
    float* __restrict__ BMX) {
  __shared__ float smax[4][64];
  int tid = threadIdx.x, wave = tid >> 6, lane = tid & 63;
  int q = lane >> 4, nl = lane & 15;
  int n = blockIdx.x * 64 + wave * 16 + nl;
  int nld = n < V_ ? n : (V_ - 1);
  const float* wr = W + (size_t)nld * H_;
  f32x4 acc[4];
  #pragma unroll
  for (int i = 0; i < 4; ++i) acc[i] = (f32x4){0.f, 0.f, 0.f, 0.f};

  for (int k0 = 0; k0 < H_; k0 += 32) {
    int kk = k0 + q * 8;
    float4 w0 = *(const float4*)(wr + kk);
    float4 w1 = *(const float4*)(wr + kk + 4);
    short8 bf = pack8(w0, w1);
    #pragma unroll
    for (int mt = 0; mt < 4; ++mt) {
      short8 af = *(const short8*)(Xb + (size_t)(mt * 16 + nl) * H_ + kk);
      acc[mt] = __builtin_amdgcn_mfma_f32_16x16x32_bf16(af, bf, acc[mt], 0, 0, 0);
    }
  }

  float bv = (n < V_) ? bias[n] : 0.f;
  #pragma unroll
  for (int mt = 0; mt < 4; ++mt)
    #pragma unroll
    for (int r = 0; r < 4; ++r) {
      float v = acc[mt][r] + bv;
      if (n < V_) P[(size_t)(mt * 16 + q * 4 + r) * VP_ + n] = v;
      float mx = (n < V_) ? v : -1e30f;
      mx = fmaxf(mx, __shfl_xor(mx, 1));
      mx = fmaxf(mx, __shfl_xor(mx, 2));
      mx = fmaxf(mx, __shfl_xor(mx, 4));
      mx = fmaxf(mx, __shfl_xor(mx, 8));
      if (nl == 0) smax[wave][mt * 16 + q * 4 + r] = mx;
    }
  __syncthreads();
  if (tid < 64) {
    float m = fmaxf(fmaxf(smax[0][tid], smax[1][tid]),
                    fmaxf(smax[2][tid], smax[3][tid]));
    BMX[(size_t)tid * BMXW_ + blockIdx.x] = m;
  }
}

// ---------------- single P pass: global row max from BMX, chunk sumexp -> SE64
__global__ __launch_bounds__(256) void k_sumexp(
    const float* __restrict__ P, const float* __restrict__ BMX,
    float* __restrict__ MXf, float* __restrict__ SE64) {
  __shared__ float red[256];
  int b = blockIdx.x >> 2, c = blockIdx.x & 3, t = threadIdx.x;
  float m = -1e30f;
  for (int i = t; i < NBV_; i += 256) m = fmaxf(m, BMX[(size_t)b * BMXW_ + i]);
  red[t] = m; __syncthreads();
  for (int s = 128; s > 0; s >>= 1) { if (t < s) red[t] = fmaxf(red[t], red[t + s]); __syncthreads(); }
  m = red[0]; __syncthreads();
  if (c == 0 && t == 0) MXf[b] = m;
  float sum = 0.f;
  int v0 = c * 12500;
  for (int v = v0 + t; v < v0 + 12500; v += 256)
    sum += __expf(P[(size_t)b * VP_ + v] - m);
  red[t] = sum; __syncthreads();
  for (int s = 128; s > 0; s >>= 1) { if (t < s) red[t] += red[t + s]; __syncthreads(); }
  if (t == 0) atomicAdd(SE64 + b, red[0]);
}

// ---------------- in-place: p_final[b][v] = p_gen*(logit - logZ) for v<V, 0 pad
__global__ void k_final(float* __restrict__ P, const float* __restrict__ pg,
                        const float* __restrict__ MXf, const float* __restrict__ SE64) {
  int b = blockIdx.y;
  float lz = MXf[b] + __logf(SE64[b]);
  float g = pg[b];
  int v0 = blockIdx.x * 1024 + threadIdx.x * 4;
  if (v0 >= VP_) return;
  float4* p = (float4*)(P + (size_t)b * VP_ + v0);
  if (v0 < V_) {                              // 50000 % 4 == 0: no mixed quad
    float4 x = *p;
    x.x = g * (x.x - lz); x.y = g * (x.y - lz);
    x.z = g * (x.z - lz); x.w = g * (x.w - lz);
    *p = x;
  } else {
    *p = make_float4(0.f, 0.f, 0.f, 0.f);
  }
}

// ---------------- pointer-copy scatter: P[b][full_input[b][l]] += (1-p_gen)*w[b][l]
__global__ void k_scatter(float* __restrict__ P, const float* __restrict__ aw,
                          const int* __restrict__ fi, const float* __restrict__ pg) {
  int b = blockIdx.x, t = threadIdx.x;
  if (t >= L_) return;
  float g = 1.f - pg[b];
  int v = fi[b * L_ + t];
  atomicAdd(P + (size_t)b * VP_ + v, g * aw[b * L_ + t]);
}

extern "C" void kernel_launch(void* const* d_in, const int* in_sizes, int n_in,
                              void* d_out, int out_size, void* d_ws, size_t ws_size,
                              hipStream_t stream) {
  const int*   ids    = (const int*)d_in[0];
  const float* hid    = (const float*)d_in[1];
  const float* enc    = (const float*)d_in[2];
  const int*   fi     = (const int*)d_in[3];
  const float* emb    = (const float*)d_in[4];
  const float* attn_W = (const float*)d_in[5];
  const float* attn_b = (const float*)d_in[6];
  const float* comb_W = (const float*)d_in[7];
  const float* comb_b = (const float*)d_in[8];
  const float* W_ih   = (const float*)d_in[9];
  const float* W_hh   = (const float*)d_in[10];
  const float* b_ih   = (const float*)d_in[11];
  const float* b_hh   = (const float*)d_in[12];
  const float* out_W  = (const float*)d_in[13];
  const float* out_b  = (const float*)d_in[14];
  const float* gen_W  = (const float*)d_in[15];
  const float* gen_b  = (const float*)d_in[16];

  float* outp    = (float*)d_out;
  float* P       = outp;                              // [64][50500]
  float* hid_out = outp + (size_t)B_ * VP_;           // [1][64][1024]
  float* aw_out  = hid_out + B_ * H_;                 // [64][400]

  float* ws = (float*)d_ws;
  float* A    = ws;                      // [64][1024] attn_applied
  float* C    = A + B_ * H_;             // [64][1024] combined
  float* S    = C + B_ * H_;             // [64][400] attn logits
  float* GI   = S + B_ * L_;             // [64][3072]
  float* GH   = GI + B_ * 3 * H_;        // [64][3072]
  float* PG   = GH + B_ * 3 * H_;        // [64]
  float* MXf  = PG + B_;                 // [64]
  float* SE64 = MXf + B_;                // [64]
  float* BMX  = SE64 + B_;               // [64][800]
  short* HNb  = (short*)(BMX + B_ * BMXW_); // [64][1024] bf16 h_new

  Job jattn = {attn_W, attn_b, emb, hid, S,  L_,     2 * H_, L_,     1};
  Job jgh   = {W_hh,   b_hh,   hid, hid, GH, 3 * H_, H_,     3 * H_, 0};
  Job jcomb = {comb_W, comb_b, emb, A,   C,  H_,     2 * H_, H_,     1};
  Job jgi   = {W_ih,   b_ih,   C,   C,   GI, 3 * H_, H_,     3 * H_, 0};

  // attn logits (25 blocks) co-launched with GH gemm (192 blocks, depends only on hid)
  k_gemm2<<<217, 256, 0, stream>>>(jattn, 25, jgh, 192,
      ids, emb, C, hid, gen_W, gen_b, PG);
  k_attnsm2<<<dim3(9, 64), 256, 0, stream>>>(S, enc, aw_out, A, hid, hid_out, SE64);
  k_gemm2<<<64, 256, 0, stream>>>(jcomb, 64, jcomb, 0,
      ids, emb, C, hid, gen_W, gen_b, PG);
  // GI gemm (192 blocks) + p_gen (64 blocks)
  k_gemm2<<<256, 256, 0, stream>>>(jgi, 192, jgi, 0,
      ids, emb, C, hid, gen_W, gen_b, PG);
  k_gru<<<256, 256, 0, stream>>>(GI, GH, hid, HNb);
  k_gemm_vocab<<<NBV_, 256, 0, stream>>>(HNb, out_W, out_b, P, BMX);
  k_sumexp<<<256, 256, 0, stream>>>(P, BMX, MXf, SE64);
  k_final<<<dim3(50, 64), 256, 0, stream>>>(P, PG, MXf, SE64);
  k_scatter<<<64, 512, 0, stream>>>(P, aw_out, fi, PG);
}